// Round 9
// baseline (7467.107 us; speedup 1.0000x reference)
//
#include <hip/hip_runtime.h>

// residual_LSTM: B=32, T=1024, H=C=512, L=2, fp32 in/out.
// R13: R12 base (store-arrival + aggregator barrier, ~6620us/dispatch) + ONE isolated
// change: L2-cached h broadcast with explicit per-step invalidation.
//  - h-path loads: sc0 only (bypass L1, ALLOCATE L2). The 16 WGs per XCD now share
//    h panels through their L2 -> LLC burst drops ~12x (12MB -> ~1MB/step).
//  - Staleness fix: each WG's wave 7, AFTER poll detect (all producer writes LLC-
//    visible), executes buffer_inv sc1 + vmcnt(0) BEFORE the closing syncthreads.
//    Every h line read afterward was fetched post-inv -> fresh by construction.
//    Redundant invs from co-XCD WGs only cause benign refetch.
//  - Inv safety prerequisite: NO dirty L2 lines -> out[] and final-state stores become
//    write-through (__hip_atomic_store relaxed agent). h-exchange stores already are.
//  - L1 never holds h lines (sc0 bypasses L1) -> no L1 staleness window.
// Carried from R12: parallel store arrival + WG0-wave6 aggregator + single-flag poll,
// wave-role barrier (nothing precedes arrival), deferred out stores + x VGPR prefetch
// in the poll window, 2-deep packed hi|lo bf16 exchange, resid prefetch, fast exp/rcp,
// LDS-resident swizzled split-precision weights.

typedef unsigned int uint32;
typedef unsigned short ushort;

constexpr int B = 32, T = 1024, H = 512, NL = 2;
constexpr int KTOT = 2 * H;            // 1024 (combined [x;h] k-dim)
constexpr int BH   = B * H;            // 16384
constexpr size_t BTH = (size_t)B * T * H;
constexpr size_t BLH = (size_t)B * NL * H;

using bf16x8  = __attribute__((ext_vector_type(8))) short;
using floatx4 = __attribute__((ext_vector_type(4))) float;
using uint4v  = __attribute__((ext_vector_type(4))) uint32;

__device__ __forceinline__ float frcp(float x) { return __builtin_amdgcn_rcpf(x); }
__device__ __forceinline__ float sigm(float v) { return frcp(1.0f + __expf(-v)); }
__device__ __forceinline__ float tanh_fast(float v) {
    return 1.0f - 2.0f * frcp(1.0f + __expf(2.0f * v));
}

__device__ __forceinline__ ushort f2bf(float f) {        // RNE fp32 -> bf16 bits
    uint32 u = __builtin_bit_cast(uint32, f);
    u += 0x7fffu + ((u >> 16) & 1u);
    return (ushort)(u >> 16);
}

__launch_bounds__(512, 1)
__global__ void lstm_persist(const float* __restrict__ x,
                             const float* __restrict__ Wi,
                             const float* __restrict__ bi,
                             const float* __restrict__ Ws,
                             const float* __restrict__ bs,
                             float* __restrict__ out,
                             uint32* __restrict__ ctrl,
                             uint32* __restrict__ h0pk,   // [2][B][H] packed hi|lo<<16
                             uint32* __restrict__ h1pk)   // [2][B][H]
{
    extern __shared__ short smem[];
    short* whi = smem;                       // [32 rows][1024 k] bf16, swizzled 16B chunks
    short* wlo = smem + 32 * KTOT;
    float* red = (float*)(smem + 64 * KTOT); // [8 waves][2 nt][64 lanes][4] fp32 (16KB)

    const int wg    = blockIdx.x;            // 0..127
    const int tid   = threadIdx.x;           // 0..511
    const int layer = wg & 1;
    const int rg    = wg >> 1;               // row-group 0..63
    const int chb   = rg * 8;                // 8 channels per WG

    // ---- stage + hi/lo split weights into LDS (once). local row n = gate*8 + c ----
    for (int i = tid; i < 32 * KTOT; i += 512) {
        const int n = i >> 10, k = i & (KTOT - 1);
        const int g = n >> 3, c = n & 7;
        const int grow = g * H + chb + c;
        const float v = (k < H) ? Wi[((size_t)layer * 4 * H + grow) * H + k]
                                : Ws[((size_t)layer * 4 * H + grow) * H + (k - H)];
        const ushort hb = f2bf(v);
        const float  hf = __builtin_bit_cast(float, (uint32)hb << 16);
        const ushort lb = f2bf(v - hf);
        const int off = (n * 128 + ((k >> 3) ^ n)) * 8 + (k & 7);   // XOR chunk swizzle
        whi[off] = (short)hb;
        wlo[off] = (short)lb;
    }

    const int lane = tid & 63;
    const int w    = tid >> 6;               // wave 0..7
    const int mt   = w & 1;                  // M-tile (batches mt*16..mt*16+15)
    const int kq   = w >> 1;                 // k-quarter (256 k each)
    const int quad = lane >> 4;
    const int mrow = lane & 15;
    const int bb   = mt * 16 + mrow;         // this lane's batch in A-frag
    const int nn   = mrow;                   // this lane's row within a B-tile

    const int ec = tid & 7, eb = tid >> 3;   // epilogue mapping (tid < 256)
    float cs = 0.f;
    float bias_[4] = {0.f, 0.f, 0.f, 0.f};
    if (tid < 256) {
        #pragma unroll
        for (int g = 0; g < 4; ++g) {
            const int grow = g * H + chb + ec;
            bias_[g] = bi[layer * 4 * H + grow] + bs[layer * 4 * H + grow];
        }
    }

    // ---- x prefetch registers (L0 x-path waves = waves 0-3): x(t) resident in VGPRs ----
    const bool xwave = (layer == 0) && (kq < 2);
    float4 xq[16];
    if (xwave) {
        const float* xb = x + ((size_t)bb * T + 0) * H + kq * 256 + quad * 8;
        #pragma unroll
        for (int st = 0; st < 8; ++st) {
            xq[2 * st]     = *(const float4*)(xb + st * 32);
            xq[2 * st + 1] = *(const float4*)(xb + st * 32 + 4);
        }
    }
    __syncthreads();

    for (int s = 0; s <= T; ++s) {
        const int t = (layer == 0) ? s : s - 1;
        const bool active = (t >= 0 && t < T);

        // ---- residual prefetch: issued before MFMA work, consumed in epilogue ----
        float resid = 0.f;
        if (active && tid < 256) {
            const int ch = chb + ec;
            if (layer == 0) {
                resid = x[((size_t)eb * T + t) * H + ch];
            } else {
                const uint32 rp = __hip_atomic_load(
                    &h0pk[(size_t)(t & 1) * BH + (size_t)eb * H + ch],
                    __ATOMIC_RELAXED, __HIP_MEMORY_SCOPE_AGENT);
                resid = __builtin_bit_cast(float, rp << 16)
                      + __builtin_bit_cast(float, rp & 0xffff0000u);
            }
        }

        if (active) {
            floatx4 acc0 = {0.f, 0.f, 0.f, 0.f};   // nt0 hi
            floatx4 acc1 = {0.f, 0.f, 0.f, 0.f};   // nt0 lo-corrections
            floatx4 acc2 = {0.f, 0.f, 0.f, 0.f};   // nt1 hi
            floatx4 acc3 = {0.f, 0.f, 0.f, 0.f};   // nt1 lo-corrections

            if (xwave) {
                // x path: data already in VGPRs (prefetched during last poll window)
                #pragma unroll
                for (int st = 0; st < 8; ++st) {
                    const float4 f0 = xq[2 * st], f1 = xq[2 * st + 1];
                    const float vv[8] = {f0.x, f0.y, f0.z, f0.w, f1.x, f1.y, f1.z, f1.w};
                    bf16x8 ahi, alo;
                    #pragma unroll
                    for (int j = 0; j < 8; ++j) {
                        const ushort hb = f2bf(vv[j]);
                        const float  hf = __builtin_bit_cast(float, (uint32)hb << 16);
                        ahi[j] = (short)hb;
                        alo[j] = (short)f2bf(vv[j] - hf);
                    }
                    const int cb = kq * 32 + st * 4 + quad;
                    const int n1 = 16 + nn;
                    const int woff0 = (nn * 128 + (cb ^ nn)) * 8;
                    const int woff1 = (n1 * 128 + (cb ^ n1)) * 8;
                    const bf16x8 bh0 = *(const bf16x8*)(whi + woff0);
                    const bf16x8 bl0 = *(const bf16x8*)(wlo + woff0);
                    const bf16x8 bh1 = *(const bf16x8*)(whi + woff1);
                    const bf16x8 bl1 = *(const bf16x8*)(wlo + woff1);
                    acc0 = __builtin_amdgcn_mfma_f32_16x16x32_bf16(ahi, bh0, acc0, 0, 0, 0);
                    acc1 = __builtin_amdgcn_mfma_f32_16x16x32_bf16(alo, bh0, acc1, 0, 0, 0);
                    acc1 = __builtin_amdgcn_mfma_f32_16x16x32_bf16(ahi, bl0, acc1, 0, 0, 0);
                    acc2 = __builtin_amdgcn_mfma_f32_16x16x32_bf16(ahi, bh1, acc2, 0, 0, 0);
                    acc3 = __builtin_amdgcn_mfma_f32_16x16x32_bf16(alo, bh1, acc3, 0, 0, 0);
                    acc3 = __builtin_amdgcn_mfma_f32_16x16x32_bf16(ahi, bl1, acc3, 0, 0, 0);
                }
            } else {
                // h path: packed loads, sc0 only -> bypass L1, ALLOCATE L2.
                // Freshness: this WG's wave 7 ran buffer_inv after the release detect,
                // before the closing sync -> every line fetched here is post-inv fresh.
                int par, koff;
                const uint32* hbuf;
                if (layer == 0)   { par = (t - 1) & 1; koff = kq * 256 - 512; hbuf = h0pk; }
                else if (kq < 2)  { par = t & 1;       koff = kq * 256;       hbuf = h0pk; }
                else              { par = (t - 1) & 1; koff = kq * 256 - 512; hbuf = h1pk; }
                const uint32* hp = hbuf + (size_t)par * BH + (size_t)bb * H + koff + quad * 8;

                uint4v q0,q1,q2,q3,q4,q5,q6,q7,q8,q9,q10,q11,q12,q13,q14,q15;
                asm volatile(
                    "global_load_dwordx4 %0,  %16, off sc0\n\t"
                    "global_load_dwordx4 %1,  %16, off offset:16 sc0\n\t"
                    "global_load_dwordx4 %2,  %16, off offset:128 sc0\n\t"
                    "global_load_dwordx4 %3,  %16, off offset:144 sc0\n\t"
                    "global_load_dwordx4 %4,  %16, off offset:256 sc0\n\t"
                    "global_load_dwordx4 %5,  %16, off offset:272 sc0\n\t"
                    "global_load_dwordx4 %6,  %16, off offset:384 sc0\n\t"
                    "global_load_dwordx4 %7,  %16, off offset:400 sc0\n\t"
                    "global_load_dwordx4 %8,  %16, off offset:512 sc0\n\t"
                    "global_load_dwordx4 %9,  %16, off offset:528 sc0\n\t"
                    "global_load_dwordx4 %10, %16, off offset:640 sc0\n\t"
                    "global_load_dwordx4 %11, %16, off offset:656 sc0\n\t"
                    "global_load_dwordx4 %12, %16, off offset:768 sc0\n\t"
                    "global_load_dwordx4 %13, %16, off offset:784 sc0\n\t"
                    "global_load_dwordx4 %14, %16, off offset:896 sc0\n\t"
                    "global_load_dwordx4 %15, %16, off offset:912 sc0\n\t"
                    "s_waitcnt vmcnt(0)"
                    : "=&v"(q0), "=&v"(q1), "=&v"(q2), "=&v"(q3),
                      "=&v"(q4), "=&v"(q5), "=&v"(q6), "=&v"(q7),
                      "=&v"(q8), "=&v"(q9), "=&v"(q10), "=&v"(q11),
                      "=&v"(q12), "=&v"(q13), "=&v"(q14), "=&v"(q15)
                    : "v"(hp)
                    : "memory");
                const uint4v qq[16] = {q0,q1,q2,q3,q4,q5,q6,q7,q8,q9,q10,q11,q12,q13,q14,q15};

                #pragma unroll
                for (int st = 0; st < 8; ++st) {
                    const uint4v ea = qq[2 * st], eb4 = qq[2 * st + 1];   // elems 0-3, 4-7
                    uint4v hiw, low;
                    hiw[0] = __builtin_amdgcn_perm(ea[1],  ea[0],  0x05040100u);
                    hiw[1] = __builtin_amdgcn_perm(ea[3],  ea[2],  0x05040100u);
                    hiw[2] = __builtin_amdgcn_perm(eb4[1], eb4[0], 0x05040100u);
                    hiw[3] = __builtin_amdgcn_perm(eb4[3], eb4[2], 0x05040100u);
                    low[0] = __builtin_amdgcn_perm(ea[1],  ea[0],  0x07060302u);
                    low[1] = __builtin_amdgcn_perm(ea[3],  ea[2],  0x07060302u);
                    low[2] = __builtin_amdgcn_perm(eb4[1], eb4[0], 0x07060302u);
                    low[3] = __builtin_amdgcn_perm(eb4[3], eb4[2], 0x07060302u);
                    const bf16x8 ahi = __builtin_bit_cast(bf16x8, hiw);
                    const bf16x8 alo = __builtin_bit_cast(bf16x8, low);
                    const int cb = kq * 32 + st * 4 + quad;
                    const int n1 = 16 + nn;
                    const int woff0 = (nn * 128 + (cb ^ nn)) * 8;
                    const int woff1 = (n1 * 128 + (cb ^ n1)) * 8;
                    const bf16x8 bh0 = *(const bf16x8*)(whi + woff0);
                    const bf16x8 bl0 = *(const bf16x8*)(wlo + woff0);
                    const bf16x8 bh1 = *(const bf16x8*)(whi + woff1);
                    const bf16x8 bl1 = *(const bf16x8*)(wlo + woff1);
                    acc0 = __builtin_amdgcn_mfma_f32_16x16x32_bf16(ahi, bh0, acc0, 0, 0, 0);
                    acc1 = __builtin_amdgcn_mfma_f32_16x16x32_bf16(alo, bh0, acc1, 0, 0, 0);
                    acc1 = __builtin_amdgcn_mfma_f32_16x16x32_bf16(ahi, bl0, acc1, 0, 0, 0);
                    acc2 = __builtin_amdgcn_mfma_f32_16x16x32_bf16(ahi, bh1, acc2, 0, 0, 0);
                    acc3 = __builtin_amdgcn_mfma_f32_16x16x32_bf16(alo, bh1, acc3, 0, 0, 0);
                    acc3 = __builtin_amdgcn_mfma_f32_16x16x32_bf16(ahi, bl1, acc3, 0, 0, 0);
                }
            }
            floatx4 zr0, zr1;
            zr0[0] = acc0[0] + acc1[0]; zr0[1] = acc0[1] + acc1[1];
            zr0[2] = acc0[2] + acc1[2]; zr0[3] = acc0[3] + acc1[3];
            zr1[0] = acc2[0] + acc3[0]; zr1[1] = acc2[1] + acc3[1];
            zr1[2] = acc2[2] + acc3[2]; zr1[3] = acc2[3] + acc3[3];
            *(floatx4*)&red[((w * 2 + 0) * 64 + lane) * 4] = zr0;
            *(floatx4*)&red[((w * 2 + 1) * 64 + lane) * 4] = zr1;
        }
        __syncthreads();   // red visible to epilogue

        float hn_s = 0.f;
        if (active && tid < 256) {
            // D layout (m89): col = lane&15, row(m) = (lane>>4)*4 + reg
            const int m = eb & 15, emt = eb >> 4, q = m >> 2, r = m & 3;
            const int ch = chb + ec;
            float z[4];
            #pragma unroll
            for (int g = 0; g < 4; ++g) {
                const int n = g * 8 + ec;          // local row 0..31
                const int nt = n >> 4, col = n & 15;
                const int li = q * 16 + col;
                float a = bias_[g];
                #pragma unroll
                for (int kqe = 0; kqe < 4; ++kqe)
                    a += red[((((kqe * 2 + emt) * 2) + nt) * 64 + li) * 4 + r];
                z[g] = a;
            }
            const float ig = sigm(z[0]), fg = sigm(z[1]);
            const float gg = tanh_fast(z[2]), og = sigm(z[3]);
            cs = ig * gg + fg * cs;
            hn_s = og * tanh_fast(cs) + resid;

            const ushort hb = f2bf(hn_s);
            const float  hf = __builtin_bit_cast(float, (uint32)hb << 16);
            const ushort lb = f2bf(hn_s - hf);
            const uint32 pk = (uint32)hb | ((uint32)lb << 16);
            const size_t hidx = (size_t)(t & 1) * BH + (size_t)eb * H + ch;
            if (layer == 0) {
                __hip_atomic_store(&h0pk[hidx], pk, __ATOMIC_RELAXED, __HIP_MEMORY_SCOPE_AGENT);
            } else {
                __hip_atomic_store(&h1pk[hidx], pk, __ATOMIC_RELAXED, __HIP_MEMORY_SCOPE_AGENT);
            }
        }

        // Drain point: h stores LLC-visible before arrival. Everything below overlaps
        // the barrier: wave 7 arrives FIRST (one plain store, nothing precedes it),
        // WG0's wave 6 aggregates, waves 0-3 issue out stores + x prefetch into the
        // poll window, then park at the closing sync.
        __syncthreads();

        // Arrival: parallel per-WG slot store (no RMW chain).
        if (tid == 448 && s < T) {
            __hip_atomic_store(&ctrl[256 + wg], (uint32)s + 1u,
                               __ATOMIC_RELAXED, __HIP_MEMORY_SCOPE_AGENT);
        }

        // Waves 0-3: deferred out stores. WRITE-THROUGH (relaxed agent) so no dirty
        // L2 lines ever exist -> the per-step buffer_inv can never discard data.
        if (active && tid < 256) {
            const int ch = chb + ec;
            if (layer == 1)
                __hip_atomic_store(&out[((size_t)eb * T + t) * H + ch], hn_s,
                                   __ATOMIC_RELAXED, __HIP_MEMORY_SCOPE_AGENT);
            if (t == T - 1) {
                __hip_atomic_store(&out[BTH + ((size_t)eb * NL + layer) * H + ch], hn_s,
                                   __ATOMIC_RELAXED, __HIP_MEMORY_SCOPE_AGENT);
                __hip_atomic_store(&out[BTH + BLH + ((size_t)eb * NL + layer) * H + ch], cs,
                                   __ATOMIC_RELAXED, __HIP_MEMORY_SCOPE_AGENT);
            }
        }

        if (s < T) {
            // Waves 0-1 group (xwave): prefetch x(s+1) into VGPRs during poll window.
            if (xwave && (s + 1) < T) {
                const float* xb = x + ((size_t)bb * T + (s + 1)) * H + kq * 256 + quad * 8;
                #pragma unroll
                for (int st = 0; st < 8; ++st) {
                    xq[2 * st]     = *(const float4*)(xb + st * 32);
                    xq[2 * st + 1] = *(const float4*)(xb + st * 32 + 4);
                }
            }
            const uint32 e = (uint32)s + 1u;
            // Aggregator: WG0 wave 6 gathers all 128 slots (2 lane-indexed loads,
            // throttled spin), then publishes the single release flag.
            if (wg == 0 && tid >= 384 && tid < 448) {
                const uint32* p0 = ctrl + 256 + (tid & 63);
                const uint32* p1 = ctrl + 320 + (tid & 63);
                for (;;) {
                    uint32 a, b;
                    asm volatile("global_load_dword %0, %2, off sc0 sc1\n\t"
                                 "global_load_dword %1, %3, off sc0 sc1\n\t"
                                 "s_waitcnt vmcnt(0)"
                                 : "=&v"(a), "=&v"(b)
                                 : "v"(p0), "v"(p1)
                                 : "memory");
                    if (__all((a >= e) && (b >= e))) break;
                    __builtin_amdgcn_s_sleep(1);
                }
                if (tid == 384)
                    __hip_atomic_store(&ctrl[512], e,
                                       __ATOMIC_RELAXED, __HIP_MEMORY_SCOPE_AGENT);
            }
            // Release: wave 7 polls the single flag dword (one 64B line, broadcast),
            // then invalidates this XCD's L2 (all producer writes are LLC-visible by
            // now) so next step's sc0 h-loads refetch fresh lines into L2.
            if (tid >= 448) {
                const uint32* fp = ctrl + 512;
                for (;;) {
                    uint32 f;
                    asm volatile("global_load_dword %0, %1, off sc0 sc1\n\t"
                                 "s_waitcnt vmcnt(0)"
                                 : "=v"(f) : "v"(fp) : "memory");
                    if (__all(f >= e)) break;
                    __builtin_amdgcn_s_sleep(1);
                }
                asm volatile("buffer_inv sc1\n\t"
                             "s_waitcnt vmcnt(0)" ::: "memory");
            }
            __syncthreads();
        }
    }
}

extern "C" void kernel_launch(void* const* d_in, const int* in_sizes, int n_in,
                              void* d_out, int out_size, void* d_ws, size_t ws_size,
                              hipStream_t stream) {
    const float* x  = (const float*)d_in[0];
    const float* Wi = (const float*)d_in[1];
    const float* bi = (const float*)d_in[2];
    const float* Ws = (const float*)d_in[3];
    const float* bs = (const float*)d_in[4];
    float* out = (float*)d_out;

    // ws: ctrl 4KB (slots @ +1024B: 128 x u32; flag @ +2048B) | h0pk 128KB | h1pk 128KB
    char* wsb = (char*)d_ws;
    uint32* ctrl = (uint32*)wsb;
    uint32* h0pk = (uint32*)(wsb + 4096);
    uint32* h1pk = (uint32*)(wsb + 4096 + 131072);
    const size_t zero_bytes = 4096 + 2 * 131072;   // 266240

    static const size_t lds_bytes = (size_t)(64 * KTOT) * sizeof(short)
                                  + (size_t)8 * 2 * 64 * 4 * sizeof(float); // 147456
    hipFuncSetAttribute((const void*)lstm_persist,
                        hipFuncAttributeMaxDynamicSharedMemorySize, (int)lds_bytes);

    hipMemsetAsync(d_ws, 0, zero_bytes, stream);
    hipLaunchKernelGGL(lstm_persist, dim3(128), dim3(512), lds_bytes, stream,
                       x, Wi, bi, Ws, bs, out, ctrl, h0pk, h1pk);
}

// Round 10
// 6616.396 us; speedup vs baseline: 1.1286x; 1.1286x over previous
//
#include <hip/hip_runtime.h>

// residual_LSTM: B=32, T=1024, H=C=512, L=2, fp32 in/out.
// R14: R12 base restored (R13's L2-cached h + buffer_inv closed: +13%, h burst is NOT
// bandwidth-limited) + ONE isolated change: fused counter barrier.
//  - Arrival: each WG's wave 7 does ONE fetch_add on a single global counter ctrl[0]
//    (nothing precedes it; R12 proved same-line RMWs pipeline well). The WG receiving
//    rr == 128*e-1 KNOWS it is last (zero detect latency) and stores the release flag.
//  - Release: all wave-7s poll the single flag line (proven R6/R9/R12 pattern).
//  - Deletes the R12 aggregator middleman: straggler->flag ~2.1k cy -> ~1.05k cy.
// Carried from R12: 128 WGs x 8ch (layer=wg&1), 2-deep h0pk/h1pk packed hi|lo bf16
// exchange (sc0 sc1, no fences), wave-role barrier, deferred out stores + x VGPR
// prefetch in the poll window, resid prefetch, fast exp/rcp, LDS-resident swizzled
// split-precision weights.

typedef unsigned int uint32;
typedef unsigned short ushort;

constexpr int B = 32, T = 1024, H = 512, NL = 2;
constexpr int KTOT = 2 * H;            // 1024 (combined [x;h] k-dim)
constexpr int BH   = B * H;            // 16384
constexpr size_t BTH = (size_t)B * T * H;
constexpr size_t BLH = (size_t)B * NL * H;

using bf16x8  = __attribute__((ext_vector_type(8))) short;
using floatx4 = __attribute__((ext_vector_type(4))) float;
using uint4v  = __attribute__((ext_vector_type(4))) uint32;

__device__ __forceinline__ float frcp(float x) { return __builtin_amdgcn_rcpf(x); }
__device__ __forceinline__ float sigm(float v) { return frcp(1.0f + __expf(-v)); }
__device__ __forceinline__ float tanh_fast(float v) {
    return 1.0f - 2.0f * frcp(1.0f + __expf(2.0f * v));
}

__device__ __forceinline__ ushort f2bf(float f) {        // RNE fp32 -> bf16 bits
    uint32 u = __builtin_bit_cast(uint32, f);
    u += 0x7fffu + ((u >> 16) & 1u);
    return (ushort)(u >> 16);
}

__launch_bounds__(512, 1)
__global__ void lstm_persist(const float* __restrict__ x,
                             const float* __restrict__ Wi,
                             const float* __restrict__ bi,
                             const float* __restrict__ Ws,
                             const float* __restrict__ bs,
                             float* __restrict__ out,
                             uint32* __restrict__ ctrl,
                             uint32* __restrict__ h0pk,   // [2][B][H] packed hi|lo<<16
                             uint32* __restrict__ h1pk)   // [2][B][H]
{
    extern __shared__ short smem[];
    short* whi = smem;                       // [32 rows][1024 k] bf16, swizzled 16B chunks
    short* wlo = smem + 32 * KTOT;
    float* red = (float*)(smem + 64 * KTOT); // [8 waves][2 nt][64 lanes][4] fp32 (16KB)

    const int wg    = blockIdx.x;            // 0..127
    const int tid   = threadIdx.x;           // 0..511
    const int layer = wg & 1;
    const int rg    = wg >> 1;               // row-group 0..63
    const int chb   = rg * 8;                // 8 channels per WG

    // ---- stage + hi/lo split weights into LDS (once). local row n = gate*8 + c ----
    for (int i = tid; i < 32 * KTOT; i += 512) {
        const int n = i >> 10, k = i & (KTOT - 1);
        const int g = n >> 3, c = n & 7;
        const int grow = g * H + chb + c;
        const float v = (k < H) ? Wi[((size_t)layer * 4 * H + grow) * H + k]
                                : Ws[((size_t)layer * 4 * H + grow) * H + (k - H)];
        const ushort hb = f2bf(v);
        const float  hf = __builtin_bit_cast(float, (uint32)hb << 16);
        const ushort lb = f2bf(v - hf);
        const int off = (n * 128 + ((k >> 3) ^ n)) * 8 + (k & 7);   // XOR chunk swizzle
        whi[off] = (short)hb;
        wlo[off] = (short)lb;
    }

    const int lane = tid & 63;
    const int w    = tid >> 6;               // wave 0..7
    const int mt   = w & 1;                  // M-tile (batches mt*16..mt*16+15)
    const int kq   = w >> 1;                 // k-quarter (256 k each)
    const int quad = lane >> 4;
    const int mrow = lane & 15;
    const int bb   = mt * 16 + mrow;         // this lane's batch in A-frag
    const int nn   = mrow;                   // this lane's row within a B-tile

    const int ec = tid & 7, eb = tid >> 3;   // epilogue mapping (tid < 256)
    float cs = 0.f;
    float bias_[4] = {0.f, 0.f, 0.f, 0.f};
    if (tid < 256) {
        #pragma unroll
        for (int g = 0; g < 4; ++g) {
            const int grow = g * H + chb + ec;
            bias_[g] = bi[layer * 4 * H + grow] + bs[layer * 4 * H + grow];
        }
    }

    // ---- x prefetch registers (L0 x-path waves = waves 0-3): x(t) resident in VGPRs ----
    const bool xwave = (layer == 0) && (kq < 2);
    float4 xq[16];
    if (xwave) {
        const float* xb = x + ((size_t)bb * T + 0) * H + kq * 256 + quad * 8;
        #pragma unroll
        for (int st = 0; st < 8; ++st) {
            xq[2 * st]     = *(const float4*)(xb + st * 32);
            xq[2 * st + 1] = *(const float4*)(xb + st * 32 + 4);
        }
    }
    __syncthreads();

    for (int s = 0; s <= T; ++s) {
        const int t = (layer == 0) ? s : s - 1;
        const bool active = (t >= 0 && t < T);

        // ---- residual prefetch: issued before MFMA work, consumed in epilogue ----
        float resid = 0.f;
        if (active && tid < 256) {
            const int ch = chb + ec;
            if (layer == 0) {
                resid = x[((size_t)eb * T + t) * H + ch];
            } else {
                const uint32 rp = __hip_atomic_load(
                    &h0pk[(size_t)(t & 1) * BH + (size_t)eb * H + ch],
                    __ATOMIC_RELAXED, __HIP_MEMORY_SCOPE_AGENT);
                resid = __builtin_bit_cast(float, rp << 16)
                      + __builtin_bit_cast(float, rp & 0xffff0000u);
            }
        }

        if (active) {
            floatx4 acc0 = {0.f, 0.f, 0.f, 0.f};   // nt0 hi
            floatx4 acc1 = {0.f, 0.f, 0.f, 0.f};   // nt0 lo-corrections
            floatx4 acc2 = {0.f, 0.f, 0.f, 0.f};   // nt1 hi
            floatx4 acc3 = {0.f, 0.f, 0.f, 0.f};   // nt1 lo-corrections

            if (xwave) {
                // x path: data already in VGPRs (prefetched during last poll window)
                #pragma unroll
                for (int st = 0; st < 8; ++st) {
                    const float4 f0 = xq[2 * st], f1 = xq[2 * st + 1];
                    const float vv[8] = {f0.x, f0.y, f0.z, f0.w, f1.x, f1.y, f1.z, f1.w};
                    bf16x8 ahi, alo;
                    #pragma unroll
                    for (int j = 0; j < 8; ++j) {
                        const ushort hb = f2bf(vv[j]);
                        const float  hf = __builtin_bit_cast(float, (uint32)hb << 16);
                        ahi[j] = (short)hb;
                        alo[j] = (short)f2bf(vv[j] - hf);
                    }
                    const int cb = kq * 32 + st * 4 + quad;
                    const int n1 = 16 + nn;
                    const int woff0 = (nn * 128 + (cb ^ nn)) * 8;
                    const int woff1 = (n1 * 128 + (cb ^ n1)) * 8;
                    const bf16x8 bh0 = *(const bf16x8*)(whi + woff0);
                    const bf16x8 bl0 = *(const bf16x8*)(wlo + woff0);
                    const bf16x8 bh1 = *(const bf16x8*)(whi + woff1);
                    const bf16x8 bl1 = *(const bf16x8*)(wlo + woff1);
                    acc0 = __builtin_amdgcn_mfma_f32_16x16x32_bf16(ahi, bh0, acc0, 0, 0, 0);
                    acc1 = __builtin_amdgcn_mfma_f32_16x16x32_bf16(alo, bh0, acc1, 0, 0, 0);
                    acc1 = __builtin_amdgcn_mfma_f32_16x16x32_bf16(ahi, bl0, acc1, 0, 0, 0);
                    acc2 = __builtin_amdgcn_mfma_f32_16x16x32_bf16(ahi, bh1, acc2, 0, 0, 0);
                    acc3 = __builtin_amdgcn_mfma_f32_16x16x32_bf16(alo, bh1, acc3, 0, 0, 0);
                    acc3 = __builtin_amdgcn_mfma_f32_16x16x32_bf16(ahi, bl1, acc3, 0, 0, 0);
                }
            } else {
                // h path: packed coherent loads direct from LLC (sc0 sc1), one vmcnt wait
                int par, koff;
                const uint32* hbuf;
                if (layer == 0)   { par = (t - 1) & 1; koff = kq * 256 - 512; hbuf = h0pk; }
                else if (kq < 2)  { par = t & 1;       koff = kq * 256;       hbuf = h0pk; }
                else              { par = (t - 1) & 1; koff = kq * 256 - 512; hbuf = h1pk; }
                const uint32* hp = hbuf + (size_t)par * BH + (size_t)bb * H + koff + quad * 8;

                uint4v q0,q1,q2,q3,q4,q5,q6,q7,q8,q9,q10,q11,q12,q13,q14,q15;
                asm volatile(
                    "global_load_dwordx4 %0,  %16, off sc0 sc1\n\t"
                    "global_load_dwordx4 %1,  %16, off offset:16 sc0 sc1\n\t"
                    "global_load_dwordx4 %2,  %16, off offset:128 sc0 sc1\n\t"
                    "global_load_dwordx4 %3,  %16, off offset:144 sc0 sc1\n\t"
                    "global_load_dwordx4 %4,  %16, off offset:256 sc0 sc1\n\t"
                    "global_load_dwordx4 %5,  %16, off offset:272 sc0 sc1\n\t"
                    "global_load_dwordx4 %6,  %16, off offset:384 sc0 sc1\n\t"
                    "global_load_dwordx4 %7,  %16, off offset:400 sc0 sc1\n\t"
                    "global_load_dwordx4 %8,  %16, off offset:512 sc0 sc1\n\t"
                    "global_load_dwordx4 %9,  %16, off offset:528 sc0 sc1\n\t"
                    "global_load_dwordx4 %10, %16, off offset:640 sc0 sc1\n\t"
                    "global_load_dwordx4 %11, %16, off offset:656 sc0 sc1\n\t"
                    "global_load_dwordx4 %12, %16, off offset:768 sc0 sc1\n\t"
                    "global_load_dwordx4 %13, %16, off offset:784 sc0 sc1\n\t"
                    "global_load_dwordx4 %14, %16, off offset:896 sc0 sc1\n\t"
                    "global_load_dwordx4 %15, %16, off offset:912 sc0 sc1\n\t"
                    "s_waitcnt vmcnt(0)"
                    : "=&v"(q0), "=&v"(q1), "=&v"(q2), "=&v"(q3),
                      "=&v"(q4), "=&v"(q5), "=&v"(q6), "=&v"(q7),
                      "=&v"(q8), "=&v"(q9), "=&v"(q10), "=&v"(q11),
                      "=&v"(q12), "=&v"(q13), "=&v"(q14), "=&v"(q15)
                    : "v"(hp)
                    : "memory");
                const uint4v qq[16] = {q0,q1,q2,q3,q4,q5,q6,q7,q8,q9,q10,q11,q12,q13,q14,q15};

                #pragma unroll
                for (int st = 0; st < 8; ++st) {
                    const uint4v ea = qq[2 * st], eb4 = qq[2 * st + 1];   // elems 0-3, 4-7
                    uint4v hiw, low;
                    hiw[0] = __builtin_amdgcn_perm(ea[1],  ea[0],  0x05040100u);
                    hiw[1] = __builtin_amdgcn_perm(ea[3],  ea[2],  0x05040100u);
                    hiw[2] = __builtin_amdgcn_perm(eb4[1], eb4[0], 0x05040100u);
                    hiw[3] = __builtin_amdgcn_perm(eb4[3], eb4[2], 0x05040100u);
                    low[0] = __builtin_amdgcn_perm(ea[1],  ea[0],  0x07060302u);
                    low[1] = __builtin_amdgcn_perm(ea[3],  ea[2],  0x07060302u);
                    low[2] = __builtin_amdgcn_perm(eb4[1], eb4[0], 0x07060302u);
                    low[3] = __builtin_amdgcn_perm(eb4[3], eb4[2], 0x07060302u);
                    const bf16x8 ahi = __builtin_bit_cast(bf16x8, hiw);
                    const bf16x8 alo = __builtin_bit_cast(bf16x8, low);
                    const int cb = kq * 32 + st * 4 + quad;
                    const int n1 = 16 + nn;
                    const int woff0 = (nn * 128 + (cb ^ nn)) * 8;
                    const int woff1 = (n1 * 128 + (cb ^ n1)) * 8;
                    const bf16x8 bh0 = *(const bf16x8*)(whi + woff0);
                    const bf16x8 bl0 = *(const bf16x8*)(wlo + woff0);
                    const bf16x8 bh1 = *(const bf16x8*)(whi + woff1);
                    const bf16x8 bl1 = *(const bf16x8*)(wlo + woff1);
                    acc0 = __builtin_amdgcn_mfma_f32_16x16x32_bf16(ahi, bh0, acc0, 0, 0, 0);
                    acc1 = __builtin_amdgcn_mfma_f32_16x16x32_bf16(alo, bh0, acc1, 0, 0, 0);
                    acc1 = __builtin_amdgcn_mfma_f32_16x16x32_bf16(ahi, bl0, acc1, 0, 0, 0);
                    acc2 = __builtin_amdgcn_mfma_f32_16x16x32_bf16(ahi, bh1, acc2, 0, 0, 0);
                    acc3 = __builtin_amdgcn_mfma_f32_16x16x32_bf16(alo, bh1, acc3, 0, 0, 0);
                    acc3 = __builtin_amdgcn_mfma_f32_16x16x32_bf16(ahi, bl1, acc3, 0, 0, 0);
                }
            }
            floatx4 zr0, zr1;
            zr0[0] = acc0[0] + acc1[0]; zr0[1] = acc0[1] + acc1[1];
            zr0[2] = acc0[2] + acc1[2]; zr0[3] = acc0[3] + acc1[3];
            zr1[0] = acc2[0] + acc3[0]; zr1[1] = acc2[1] + acc3[1];
            zr1[2] = acc2[2] + acc3[2]; zr1[3] = acc2[3] + acc3[3];
            *(floatx4*)&red[((w * 2 + 0) * 64 + lane) * 4] = zr0;
            *(floatx4*)&red[((w * 2 + 1) * 64 + lane) * 4] = zr1;
        }
        __syncthreads();   // red visible to epilogue

        float hn_s = 0.f;
        if (active && tid < 256) {
            // D layout (m89): col = lane&15, row(m) = (lane>>4)*4 + reg
            const int m = eb & 15, emt = eb >> 4, q = m >> 2, r = m & 3;
            const int ch = chb + ec;
            float z[4];
            #pragma unroll
            for (int g = 0; g < 4; ++g) {
                const int n = g * 8 + ec;          // local row 0..31
                const int nt = n >> 4, col = n & 15;
                const int li = q * 16 + col;
                float a = bias_[g];
                #pragma unroll
                for (int kqe = 0; kqe < 4; ++kqe)
                    a += red[((((kqe * 2 + emt) * 2) + nt) * 64 + li) * 4 + r];
                z[g] = a;
            }
            const float ig = sigm(z[0]), fg = sigm(z[1]);
            const float gg = tanh_fast(z[2]), og = sigm(z[3]);
            cs = ig * gg + fg * cs;
            hn_s = og * tanh_fast(cs) + resid;

            const ushort hb = f2bf(hn_s);
            const float  hf = __builtin_bit_cast(float, (uint32)hb << 16);
            const ushort lb = f2bf(hn_s - hf);
            const uint32 pk = (uint32)hb | ((uint32)lb << 16);
            const size_t hidx = (size_t)(t & 1) * BH + (size_t)eb * H + ch;
            if (layer == 0) {
                __hip_atomic_store(&h0pk[hidx], pk, __ATOMIC_RELAXED, __HIP_MEMORY_SCOPE_AGENT);
            } else {
                __hip_atomic_store(&h1pk[hidx], pk, __ATOMIC_RELAXED, __HIP_MEMORY_SCOPE_AGENT);
            }
        }

        // Drain point: h stores LLC-visible before arrival. Everything below overlaps
        // the barrier: wave 7 arrives FIRST (one RMW, nothing precedes it), waves 0-3
        // issue out stores + x prefetch into the poll window, then park at the sync.
        __syncthreads();

        // Arrival: single fetch_add on ONE counter. Last arriver (rr == e*128-1)
        // publishes the release flag with zero detect latency.
        if (tid == 448 && s < T) {
            const uint32 e = (uint32)s + 1u;
            const uint32 rr = __hip_atomic_fetch_add(&ctrl[0], 1u, __ATOMIC_RELAXED,
                                                     __HIP_MEMORY_SCOPE_AGENT);
            if (rr == e * 128u - 1u)
                __hip_atomic_store(&ctrl[512], e,
                                   __ATOMIC_RELAXED, __HIP_MEMORY_SCOPE_AGENT);
        }

        // Waves 0-3: deferred out stores (out[] never read device-side).
        if (active && tid < 256) {
            const int ch = chb + ec;
            if (layer == 1)
                out[((size_t)eb * T + t) * H + ch] = hn_s;
            if (t == T - 1) {
                out[BTH + ((size_t)eb * NL + layer) * H + ch] = hn_s;
                out[BTH + BLH + ((size_t)eb * NL + layer) * H + ch] = cs;
            }
        }

        if (s < T) {
            // Waves 0-1 group (xwave): prefetch x(s+1) into VGPRs during poll window.
            if (xwave && (s + 1) < T) {
                const float* xb = x + ((size_t)bb * T + (s + 1)) * H + kq * 256 + quad * 8;
                #pragma unroll
                for (int st = 0; st < 8; ++st) {
                    xq[2 * st]     = *(const float4*)(xb + st * 32);
                    xq[2 * st + 1] = *(const float4*)(xb + st * 32 + 4);
                }
            }
            const uint32 e = (uint32)s + 1u;
            // Release: wave 7 polls the single flag dword (one 64B line, broadcast).
            if (tid >= 448) {
                const uint32* fp = ctrl + 512;
                for (;;) {
                    uint32 f;
                    asm volatile("global_load_dword %0, %1, off sc0 sc1\n\t"
                                 "s_waitcnt vmcnt(0)"
                                 : "=v"(f) : "v"(fp) : "memory");
                    if (__all(f >= e)) break;
                    __builtin_amdgcn_s_sleep(1);
                }
            }
            __syncthreads();
        }
    }
}

extern "C" void kernel_launch(void* const* d_in, const int* in_sizes, int n_in,
                              void* d_out, int out_size, void* d_ws, size_t ws_size,
                              hipStream_t stream) {
    const float* x  = (const float*)d_in[0];
    const float* Wi = (const float*)d_in[1];
    const float* bi = (const float*)d_in[2];
    const float* Ws = (const float*)d_in[3];
    const float* bs = (const float*)d_in[4];
    float* out = (float*)d_out;

    // ws: ctrl 4KB (counter @ 0, flag @ +2048B) | h0pk 128KB | h1pk 128KB
    char* wsb = (char*)d_ws;
    uint32* ctrl = (uint32*)wsb;
    uint32* h0pk = (uint32*)(wsb + 4096);
    uint32* h1pk = (uint32*)(wsb + 4096 + 131072);
    const size_t zero_bytes = 4096 + 2 * 131072;   // 266240

    static const size_t lds_bytes = (size_t)(64 * KTOT) * sizeof(short)
                                  + (size_t)8 * 2 * 64 * 4 * sizeof(float); // 147456
    hipFuncSetAttribute((const void*)lstm_persist,
                        hipFuncAttributeMaxDynamicSharedMemorySize, (int)lds_bytes);

    hipMemsetAsync(d_ws, 0, zero_bytes, stream);
    hipLaunchKernelGGL(lstm_persist, dim3(128), dim3(512), lds_bytes, stream,
                       x, Wi, bi, Ws, bs, out, ctrl, h0pk, h1pk);
}

// Round 11
// 6526.856 us; speedup vs baseline: 1.1441x; 1.0137x over previous
//
#include <hip/hip_runtime.h>

// residual_LSTM: B=32, T=1024, H=C=512, L=2, fp32 in/out.
// R15: R14 base (fused-counter barrier, 6616us) + layer-split gating, 2-deep buffers.
// R10's skew failure was the 4-deep buffer eviction (+258KB/step HBM), not skew itself.
//  - Arrivals: wave 7 fetch_add on per-layer counters (ctrl[0]=L0, ctrl[32]=L1,
//    separate lines). Last arriver (rr==64e-1) publishes its layer flag to 4 replica
//    lines (flagL0@ctrl[512+32r], flagL1@ctrl[513+32r], r=0..3, 128B apart).
//  - Gates (from clobber/visibility audit of the 2-deep exchange buffers):
//      L0 h-waves (kq>=2), top of step s:  flagL0 >= s   (own recurrence only)
//      L0 x-waves: no top gate (registers); L0 epilogue before h0pk store: flagL1 >= s
//        (protects L1's step s-1 readers of slot s&1; flagL0>=s ordered via sync1)
//      L1 all waves, top of step s: flagL0 >= s && flagL1 >= s (one dwordx2 poll)
//  - NO closing sync: waves self-poll their gates (post-release syncthreads convoy
//    gone). Wave 7 still arrives FIRST (R8 lesson). sync1/sync2 unchanged.
//  - Deadlock-free: gates reference strictly older epochs; arrivals unconditional.
// Carried from R14: 128 WGs x 8ch (layer=wg&1), 2-deep packed hi|lo bf16 exchange
// (sc0 sc1, no fences), deferred out stores + x VGPR prefetch after sync2, resid
// prefetch, fast exp/rcp, LDS-resident swizzled split-precision weights.

typedef unsigned int uint32;
typedef unsigned short ushort;

constexpr int B = 32, T = 1024, H = 512, NL = 2;
constexpr int KTOT = 2 * H;            // 1024 (combined [x;h] k-dim)
constexpr int BH   = B * H;            // 16384
constexpr size_t BTH = (size_t)B * T * H;
constexpr size_t BLH = (size_t)B * NL * H;

using bf16x8  = __attribute__((ext_vector_type(8))) short;
using floatx4 = __attribute__((ext_vector_type(4))) float;
using uint2v  = __attribute__((ext_vector_type(2))) uint32;
using uint4v  = __attribute__((ext_vector_type(4))) uint32;

__device__ __forceinline__ float frcp(float x) { return __builtin_amdgcn_rcpf(x); }
__device__ __forceinline__ float sigm(float v) { return frcp(1.0f + __expf(-v)); }
__device__ __forceinline__ float tanh_fast(float v) {
    return 1.0f - 2.0f * frcp(1.0f + __expf(2.0f * v));
}

__device__ __forceinline__ ushort f2bf(float f) {        // RNE fp32 -> bf16 bits
    uint32 u = __builtin_bit_cast(uint32, f);
    u += 0x7fffu + ((u >> 16) & 1u);
    return (ushort)(u >> 16);
}

__launch_bounds__(512, 1)
__global__ void lstm_persist(const float* __restrict__ x,
                             const float* __restrict__ Wi,
                             const float* __restrict__ bi,
                             const float* __restrict__ Ws,
                             const float* __restrict__ bs,
                             float* __restrict__ out,
                             uint32* __restrict__ ctrl,
                             uint32* __restrict__ h0pk,   // [2][B][H] packed hi|lo<<16
                             uint32* __restrict__ h1pk)   // [2][B][H]
{
    extern __shared__ short smem[];
    short* whi = smem;                       // [32 rows][1024 k] bf16, swizzled 16B chunks
    short* wlo = smem + 32 * KTOT;
    float* red = (float*)(smem + 64 * KTOT); // [8 waves][2 nt][64 lanes][4] fp32 (16KB)

    const int wg    = blockIdx.x;            // 0..127
    const int tid   = threadIdx.x;           // 0..511
    const int layer = wg & 1;
    const int rg    = wg >> 1;               // row-group 0..63
    const int chb   = rg * 8;                // 8 channels per WG

    // ---- stage + hi/lo split weights into LDS (once). local row n = gate*8 + c ----
    for (int i = tid; i < 32 * KTOT; i += 512) {
        const int n = i >> 10, k = i & (KTOT - 1);
        const int g = n >> 3, c = n & 7;
        const int grow = g * H + chb + c;
        const float v = (k < H) ? Wi[((size_t)layer * 4 * H + grow) * H + k]
                                : Ws[((size_t)layer * 4 * H + grow) * H + (k - H)];
        const ushort hb = f2bf(v);
        const float  hf = __builtin_bit_cast(float, (uint32)hb << 16);
        const ushort lb = f2bf(v - hf);
        const int off = (n * 128 + ((k >> 3) ^ n)) * 8 + (k & 7);   // XOR chunk swizzle
        whi[off] = (short)hb;
        wlo[off] = (short)lb;
    }

    const int lane = tid & 63;
    const int w    = tid >> 6;               // wave 0..7
    const int mt   = w & 1;                  // M-tile (batches mt*16..mt*16+15)
    const int kq   = w >> 1;                 // k-quarter (256 k each)
    const int quad = lane >> 4;
    const int mrow = lane & 15;
    const int bb   = mt * 16 + mrow;         // this lane's batch in A-frag
    const int nn   = mrow;                   // this lane's row within a B-tile

    const int ec = tid & 7, eb = tid >> 3;   // epilogue mapping (tid < 256)
    float cs = 0.f;
    float bias_[4] = {0.f, 0.f, 0.f, 0.f};
    if (tid < 256) {
        #pragma unroll
        for (int g = 0; g < 4; ++g) {
            const int grow = g * H + chb + ec;
            bias_[g] = bi[layer * 4 * H + grow] + bs[layer * 4 * H + grow];
        }
    }

    // flag replica line for this WG (flagL0 at +0, flagL1 at +1, dwordx2-loadable)
    const uint32* fline = ctrl + 512 + (wg & 3) * 32;

    // ---- x prefetch registers (L0 x-path waves = waves 0-3): x(t) resident in VGPRs ----
    const bool xwave = (layer == 0) && (kq < 2);
    float4 xq[16];
    if (xwave) {
        const float* xb = x + ((size_t)bb * T + 0) * H + kq * 256 + quad * 8;
        #pragma unroll
        for (int st = 0; st < 8; ++st) {
            xq[2 * st]     = *(const float4*)(xb + st * 32);
            xq[2 * st + 1] = *(const float4*)(xb + st * 32 + 4);
        }
    }
    __syncthreads();

    for (int s = 0; s <= T; ++s) {
        const int t = (layer == 0) ? s : s - 1;
        const bool active = (t >= 0 && t < T);
        const uint32 eg = (uint32)s;         // gate epoch for this step's reads

        // ---- top-of-step gates (self-poll; replaces the closing barrier sync) ----
        if (active && s > 0) {
            if (layer == 1) {
                // all L1 waves: need flagL0>=s (h0pk + resid) && flagL1>=s (h1pk)
                for (;;) {
                    uint2v f;
                    asm volatile("global_load_dwordx2 %0, %1, off sc0 sc1\n\t"
                                 "s_waitcnt vmcnt(0)"
                                 : "=v"(f) : "v"(fline) : "memory");
                    if (__all((f[0] >= eg) && (f[1] >= eg))) break;
                    __builtin_amdgcn_s_sleep(1);
                }
            } else if (kq >= 2) {
                // L0 h-waves: own-layer recurrence only
                for (;;) {
                    uint32 f;
                    asm volatile("global_load_dword %0, %1, off sc0 sc1\n\t"
                                 "s_waitcnt vmcnt(0)"
                                 : "=v"(f) : "v"(fline) : "memory");
                    if (__all(f >= eg)) break;
                    __builtin_amdgcn_s_sleep(1);
                }
            }
        }

        // ---- residual prefetch: issued before MFMA work, consumed in epilogue ----
        float resid = 0.f;
        if (active && tid < 256) {
            const int ch = chb + ec;
            if (layer == 0) {
                resid = x[((size_t)eb * T + t) * H + ch];
            } else {
                const uint32 rp = __hip_atomic_load(
                    &h0pk[(size_t)(t & 1) * BH + (size_t)eb * H + ch],
                    __ATOMIC_RELAXED, __HIP_MEMORY_SCOPE_AGENT);
                resid = __builtin_bit_cast(float, rp << 16)
                      + __builtin_bit_cast(float, rp & 0xffff0000u);
            }
        }

        if (active) {
            floatx4 acc0 = {0.f, 0.f, 0.f, 0.f};   // nt0 hi
            floatx4 acc1 = {0.f, 0.f, 0.f, 0.f};   // nt0 lo-corrections
            floatx4 acc2 = {0.f, 0.f, 0.f, 0.f};   // nt1 hi
            floatx4 acc3 = {0.f, 0.f, 0.f, 0.f};   // nt1 lo-corrections

            if (xwave) {
                // x path: data already in VGPRs (prefetched during last poll window)
                #pragma unroll
                for (int st = 0; st < 8; ++st) {
                    const float4 f0 = xq[2 * st], f1 = xq[2 * st + 1];
                    const float vv[8] = {f0.x, f0.y, f0.z, f0.w, f1.x, f1.y, f1.z, f1.w};
                    bf16x8 ahi, alo;
                    #pragma unroll
                    for (int j = 0; j < 8; ++j) {
                        const ushort hb = f2bf(vv[j]);
                        const float  hf = __builtin_bit_cast(float, (uint32)hb << 16);
                        ahi[j] = (short)hb;
                        alo[j] = (short)f2bf(vv[j] - hf);
                    }
                    const int cb = kq * 32 + st * 4 + quad;
                    const int n1 = 16 + nn;
                    const int woff0 = (nn * 128 + (cb ^ nn)) * 8;
                    const int woff1 = (n1 * 128 + (cb ^ n1)) * 8;
                    const bf16x8 bh0 = *(const bf16x8*)(whi + woff0);
                    const bf16x8 bl0 = *(const bf16x8*)(wlo + woff0);
                    const bf16x8 bh1 = *(const bf16x8*)(whi + woff1);
                    const bf16x8 bl1 = *(const bf16x8*)(wlo + woff1);
                    acc0 = __builtin_amdgcn_mfma_f32_16x16x32_bf16(ahi, bh0, acc0, 0, 0, 0);
                    acc1 = __builtin_amdgcn_mfma_f32_16x16x32_bf16(alo, bh0, acc1, 0, 0, 0);
                    acc1 = __builtin_amdgcn_mfma_f32_16x16x32_bf16(ahi, bl0, acc1, 0, 0, 0);
                    acc2 = __builtin_amdgcn_mfma_f32_16x16x32_bf16(ahi, bh1, acc2, 0, 0, 0);
                    acc3 = __builtin_amdgcn_mfma_f32_16x16x32_bf16(alo, bh1, acc3, 0, 0, 0);
                    acc3 = __builtin_amdgcn_mfma_f32_16x16x32_bf16(ahi, bl1, acc3, 0, 0, 0);
                }
            } else {
                // h path: packed coherent loads direct from LLC (sc0 sc1), one vmcnt wait
                int par, koff;
                const uint32* hbuf;
                if (layer == 0)   { par = (t - 1) & 1; koff = kq * 256 - 512; hbuf = h0pk; }
                else if (kq < 2)  { par = t & 1;       koff = kq * 256;       hbuf = h0pk; }
                else              { par = (t - 1) & 1; koff = kq * 256 - 512; hbuf = h1pk; }
                const uint32* hp = hbuf + (size_t)par * BH + (size_t)bb * H + koff + quad * 8;

                uint4v q0,q1,q2,q3,q4,q5,q6,q7,q8,q9,q10,q11,q12,q13,q14,q15;
                asm volatile(
                    "global_load_dwordx4 %0,  %16, off sc0 sc1\n\t"
                    "global_load_dwordx4 %1,  %16, off offset:16 sc0 sc1\n\t"
                    "global_load_dwordx4 %2,  %16, off offset:128 sc0 sc1\n\t"
                    "global_load_dwordx4 %3,  %16, off offset:144 sc0 sc1\n\t"
                    "global_load_dwordx4 %4,  %16, off offset:256 sc0 sc1\n\t"
                    "global_load_dwordx4 %5,  %16, off offset:272 sc0 sc1\n\t"
                    "global_load_dwordx4 %6,  %16, off offset:384 sc0 sc1\n\t"
                    "global_load_dwordx4 %7,  %16, off offset:400 sc0 sc1\n\t"
                    "global_load_dwordx4 %8,  %16, off offset:512 sc0 sc1\n\t"
                    "global_load_dwordx4 %9,  %16, off offset:528 sc0 sc1\n\t"
                    "global_load_dwordx4 %10, %16, off offset:640 sc0 sc1\n\t"
                    "global_load_dwordx4 %11, %16, off offset:656 sc0 sc1\n\t"
                    "global_load_dwordx4 %12, %16, off offset:768 sc0 sc1\n\t"
                    "global_load_dwordx4 %13, %16, off offset:784 sc0 sc1\n\t"
                    "global_load_dwordx4 %14, %16, off offset:896 sc0 sc1\n\t"
                    "global_load_dwordx4 %15, %16, off offset:912 sc0 sc1\n\t"
                    "s_waitcnt vmcnt(0)"
                    : "=&v"(q0), "=&v"(q1), "=&v"(q2), "=&v"(q3),
                      "=&v"(q4), "=&v"(q5), "=&v"(q6), "=&v"(q7),
                      "=&v"(q8), "=&v"(q9), "=&v"(q10), "=&v"(q11),
                      "=&v"(q12), "=&v"(q13), "=&v"(q14), "=&v"(q15)
                    : "v"(hp)
                    : "memory");
                const uint4v qq[16] = {q0,q1,q2,q3,q4,q5,q6,q7,q8,q9,q10,q11,q12,q13,q14,q15};

                #pragma unroll
                for (int st = 0; st < 8; ++st) {
                    const uint4v ea = qq[2 * st], eb4 = qq[2 * st + 1];   // elems 0-3, 4-7
                    uint4v hiw, low;
                    hiw[0] = __builtin_amdgcn_perm(ea[1],  ea[0],  0x05040100u);
                    hiw[1] = __builtin_amdgcn_perm(ea[3],  ea[2],  0x05040100u);
                    hiw[2] = __builtin_amdgcn_perm(eb4[1], eb4[0], 0x05040100u);
                    hiw[3] = __builtin_amdgcn_perm(eb4[3], eb4[2], 0x05040100u);
                    low[0] = __builtin_amdgcn_perm(ea[1],  ea[0],  0x07060302u);
                    low[1] = __builtin_amdgcn_perm(ea[3],  ea[2],  0x07060302u);
                    low[2] = __builtin_amdgcn_perm(eb4[1], eb4[0], 0x07060302u);
                    low[3] = __builtin_amdgcn_perm(eb4[3], eb4[2], 0x07060302u);
                    const bf16x8 ahi = __builtin_bit_cast(bf16x8, hiw);
                    const bf16x8 alo = __builtin_bit_cast(bf16x8, low);
                    const int cb = kq * 32 + st * 4 + quad;
                    const int n1 = 16 + nn;
                    const int woff0 = (nn * 128 + (cb ^ nn)) * 8;
                    const int woff1 = (n1 * 128 + (cb ^ n1)) * 8;
                    const bf16x8 bh0 = *(const bf16x8*)(whi + woff0);
                    const bf16x8 bl0 = *(const bf16x8*)(wlo + woff0);
                    const bf16x8 bh1 = *(const bf16x8*)(whi + woff1);
                    const bf16x8 bl1 = *(const bf16x8*)(wlo + woff1);
                    acc0 = __builtin_amdgcn_mfma_f32_16x16x32_bf16(ahi, bh0, acc0, 0, 0, 0);
                    acc1 = __builtin_amdgcn_mfma_f32_16x16x32_bf16(alo, bh0, acc1, 0, 0, 0);
                    acc1 = __builtin_amdgcn_mfma_f32_16x16x32_bf16(ahi, bl0, acc1, 0, 0, 0);
                    acc2 = __builtin_amdgcn_mfma_f32_16x16x32_bf16(ahi, bh1, acc2, 0, 0, 0);
                    acc3 = __builtin_amdgcn_mfma_f32_16x16x32_bf16(alo, bh1, acc3, 0, 0, 0);
                    acc3 = __builtin_amdgcn_mfma_f32_16x16x32_bf16(ahi, bl1, acc3, 0, 0, 0);
                }
            }
            floatx4 zr0, zr1;
            zr0[0] = acc0[0] + acc1[0]; zr0[1] = acc0[1] + acc1[1];
            zr0[2] = acc0[2] + acc1[2]; zr0[3] = acc0[3] + acc1[3];
            zr1[0] = acc2[0] + acc3[0]; zr1[1] = acc2[1] + acc3[1];
            zr1[2] = acc2[2] + acc3[2]; zr1[3] = acc2[3] + acc3[3];
            *(floatx4*)&red[((w * 2 + 0) * 64 + lane) * 4] = zr0;
            *(floatx4*)&red[((w * 2 + 1) * 64 + lane) * 4] = zr1;
        }
        __syncthreads();   // sync1: red visible to epilogue; orders flagL0 gate WG-wide

        float hn_s = 0.f;
        if (active && tid < 256) {
            // D layout (m89): col = lane&15, row(m) = (lane>>4)*4 + reg
            const int m = eb & 15, emt = eb >> 4, q = m >> 2, r = m & 3;
            const int ch = chb + ec;
            float z[4];
            #pragma unroll
            for (int g = 0; g < 4; ++g) {
                const int n = g * 8 + ec;          // local row 0..31
                const int nt = n >> 4, col = n & 15;
                const int li = q * 16 + col;
                float a = bias_[g];
                #pragma unroll
                for (int kqe = 0; kqe < 4; ++kqe)
                    a += red[((((kqe * 2 + emt) * 2) + nt) * 64 + li) * 4 + r];
                z[g] = a;
            }
            const float ig = sigm(z[0]), fg = sigm(z[1]);
            const float gg = tanh_fast(z[2]), og = sigm(z[3]);
            cs = ig * gg + fg * cs;
            hn_s = og * tanh_fast(cs) + resid;

            // L0 epilogue gate: h0pk slot s&1 was read by L1 at step s-1; wait for
            // L1 arrivals of epoch s before overwriting. Usually already satisfied.
            if (layer == 0 && s > 0) {
                const uint32* fl1 = fline + 1;
                for (;;) {
                    uint32 f;
                    asm volatile("global_load_dword %0, %1, off sc0 sc1\n\t"
                                 "s_waitcnt vmcnt(0)"
                                 : "=v"(f) : "v"(fl1) : "memory");
                    if (__all(f >= eg)) break;
                    __builtin_amdgcn_s_sleep(1);
                }
            }

            const ushort hb = f2bf(hn_s);
            const float  hf = __builtin_bit_cast(float, (uint32)hb << 16);
            const ushort lb = f2bf(hn_s - hf);
            const uint32 pk = (uint32)hb | ((uint32)lb << 16);
            const size_t hidx = (size_t)(t & 1) * BH + (size_t)eb * H + ch;
            if (layer == 0) {
                __hip_atomic_store(&h0pk[hidx], pk, __ATOMIC_RELAXED, __HIP_MEMORY_SCOPE_AGENT);
            } else {
                __hip_atomic_store(&h1pk[hidx], pk, __ATOMIC_RELAXED, __HIP_MEMORY_SCOPE_AGENT);
            }
        }

        // sync2 (drain): h stores LLC-visible before arrival. Everything below overlaps
        // other WGs' progress: wave 7 arrives FIRST (one RMW, nothing precedes it),
        // waves 0-3 issue out stores + x prefetch, then loop to next step's gates.
        __syncthreads();

        if (tid == 448 && s < T) {
            const uint32 e = (uint32)s + 1u;
            uint32* cnt = (layer == 0) ? &ctrl[0] : &ctrl[32];
            const uint32 rr = __hip_atomic_fetch_add(cnt, 1u, __ATOMIC_RELAXED,
                                                     __HIP_MEMORY_SCOPE_AGENT);
            if (rr == e * 64u - 1u) {
                #pragma unroll
                for (int r4 = 0; r4 < 4; ++r4)
                    __hip_atomic_store(&ctrl[512 + layer + r4 * 32], e,
                                       __ATOMIC_RELAXED, __HIP_MEMORY_SCOPE_AGENT);
            }
        }

        // Waves 0-3: deferred out stores (out[] never read device-side).
        if (active && tid < 256) {
            const int ch = chb + ec;
            if (layer == 1)
                out[((size_t)eb * T + t) * H + ch] = hn_s;
            if (t == T - 1) {
                out[BTH + ((size_t)eb * NL + layer) * H + ch] = hn_s;
                out[BTH + BLH + ((size_t)eb * NL + layer) * H + ch] = cs;
            }
        }

        // Waves 0-1 group (xwave): prefetch x(s+1) into VGPRs (overlaps gates).
        if (xwave && (s + 1) < T) {
            const float* xb = x + ((size_t)bb * T + (s + 1)) * H + kq * 256 + quad * 8;
            #pragma unroll
            for (int st = 0; st < 8; ++st) {
                xq[2 * st]     = *(const float4*)(xb + st * 32);
                xq[2 * st + 1] = *(const float4*)(xb + st * 32 + 4);
            }
        }
        // no closing syncthreads: next iteration's gates do the waiting.
    }
}

extern "C" void kernel_launch(void* const* d_in, const int* in_sizes, int n_in,
                              void* d_out, int out_size, void* d_ws, size_t ws_size,
                              hipStream_t stream) {
    const float* x  = (const float*)d_in[0];
    const float* Wi = (const float*)d_in[1];
    const float* bi = (const float*)d_in[2];
    const float* Ws = (const float*)d_in[3];
    const float* bs = (const float*)d_in[4];
    float* out = (float*)d_out;

    // ws: ctrl 4KB (cntL0@0, cntL1@32, flag replicas @512+32r: [L0,L1] dwords)
    //     | h0pk 128KB | h1pk 128KB
    char* wsb = (char*)d_ws;
    uint32* ctrl = (uint32*)wsb;
    uint32* h0pk = (uint32*)(wsb + 4096);
    uint32* h1pk = (uint32*)(wsb + 4096 + 131072);
    const size_t zero_bytes = 4096 + 2 * 131072;   // 266240

    static const size_t lds_bytes = (size_t)(64 * KTOT) * sizeof(short)
                                  + (size_t)8 * 2 * 64 * 4 * sizeof(float); // 147456
    hipFuncSetAttribute((const void*)lstm_persist,
                        hipFuncAttributeMaxDynamicSharedMemorySize, (int)lds_bytes);

    hipMemsetAsync(d_ws, 0, zero_bytes, stream);
    hipLaunchKernelGGL(lstm_persist, dim3(128), dim3(512), lds_bytes, stream,
                       x, Wi, bi, Ws, bs, out, ctrl, h0pk, h1pk);
}